// Round 9
// baseline (154.108 us; speedup 1.0000x reference)
//
#include <hip/hip_runtime.h>
#include <hip/hip_bf16.h>
#include <math.h>

#define DIM   5120
#define NH    40
#define NKV   8
#define HD    128
#define BS    8
#define KLEN  4096
#define NEWT  4095
#define NREP  5

#define ODQKV 7168          // 5120 + 1024 + 1024 combined output columns
#define NKC   32            // split-K chunks for GEMVs
#define KCH   (DIM / NKC)   // 160 rows per chunk

#define NCHB  64                // t-chunks per (b,h)
#define CH_T  (KLEN / NCHB)     // 64 rows per block
#define NPART NCHB              // partials per (b,h)

// workspace layout (in floats)
#define WS_Q       0
#define WS_K       (WS_Q + BS * DIM)        // 40960
#define WS_V       (WS_K + BS * NKV * HD)   // 49152
#define WS_ATTN    (WS_V + BS * NKV * HD)   // 57344
#define WS_SCRATCH (WS_ATTN + BS * DIM)     // 98304  (scratch reused across phases)

// direct global->LDS DMA, 16 B per lane (CK addrspace-cast idiom)
__device__ __forceinline__ void gload_lds16(const float* g, float* l) {
  __builtin_amdgcn_global_load_lds(
      (const __attribute__((address_space(1))) void*)(unsigned long long)g,
      (__attribute__((address_space(3))) void*)(unsigned int)(unsigned long long)l,
      16, 0, 0);
}

// ---------------------------------------------------------------------------
// Phase A: combined QKV GEMV, split-K partials. 2 cols/thread, float2 weight
// loads, x via wave-uniform scalar loads.
// ---------------------------------------------------------------------------
__global__ __launch_bounds__(256) void qkv_partial_k(
    const float* __restrict__ x, const float* __restrict__ wq,
    const float* __restrict__ wk, const float* __restrict__ wv,
    float* __restrict__ part) {
  const int cb = blockIdx.x % 14;
  const int kc = blockIdx.x / 14;
  const int c0 = cb * 512 + threadIdx.x * 2;   // first of 2 owned columns

  const float* w; int OD, j;
  if (c0 < 5120)      { w = wq; OD = 5120; j = c0; }
  else if (c0 < 6144) { w = wk; OD = 1024; j = c0 - 5120; }
  else                { w = wv; OD = 1024; j = c0 - 6144; }

  const int i0 = kc * KCH;
  float ax[BS], ay[BS];
#pragma unroll
  for (int b = 0; b < BS; ++b) { ax[b] = 0.f; ay[b] = 0.f; }

  const float* wp = w + (size_t)i0 * OD + j;
  const float* xp = x + i0;
#pragma unroll 4
  for (int ii = 0; ii < KCH; ++ii) {
    const float2 wv2 = *(const float2*)&wp[(size_t)ii * OD];
#pragma unroll
    for (int b = 0; b < BS; ++b) {
      const float xb = xp[b * DIM + ii];   // wave-uniform -> scalar load
      ax[b] = fmaf(xb, wv2.x, ax[b]);
      ay[b] = fmaf(xb, wv2.y, ay[b]);
    }
  }
#pragma unroll
  for (int b = 0; b < BS; ++b)
    *(float2*)&part[((size_t)kc * BS + b) * ODQKV + c0] = make_float2(ax[b], ay[b]);
}

// ---------------------------------------------------------------------------
// Phase A2: reduce partials, add bias, apply RoPE (pos 4095), fold 1/sqrt(128)
// into q.
// ---------------------------------------------------------------------------
__global__ __launch_bounds__(256) void qkv_reduce_k(
    const float* __restrict__ part, const float* __restrict__ bq,
    const float* __restrict__ bk, const float* __restrict__ bv,
    const float* __restrict__ fc, float* __restrict__ qws,
    float* __restrict__ kws, float* __restrict__ vws) {
  int g = blockIdx.x * 256 + threadIdx.x;
  if (g >= BS * (ODQKV / 2)) return;
  int b  = g / (ODQKV / 2);
  int cp = g - b * (ODQKV / 2);
  int c0 = cp * 2;

  float sx = 0.f, sy = 0.f;
  for (int kc = 0; kc < NKC; ++kc) {
    const float2 p = *(const float2*)&part[((size_t)kc * BS + b) * ODQKV + c0];
    sx += p.x; sy += p.y;
  }

  const float scale = 0.088388347648318447f;  // 1/sqrt(128)
  if (c0 < 5120) {
    sx += bq[c0]; sy += bq[c0 + 1];
    int jf = (c0 & 127) >> 1;
    float cs = fc[2 * jf], sn = fc[2 * jf + 1];
    qws[b * DIM + c0]     = (sx * cs - sy * sn) * scale;
    qws[b * DIM + c0 + 1] = (sx * sn + sy * cs) * scale;
  } else if (c0 < 6144) {
    int jj = c0 - 5120;
    sx += bk[jj]; sy += bk[jj + 1];
    int jf = (jj & 127) >> 1;
    float cs = fc[2 * jf], sn = fc[2 * jf + 1];
    kws[b * NKV * HD + jj]     = sx * cs - sy * sn;
    kws[b * NKV * HD + jj + 1] = sx * sn + sy * cs;
  } else {
    int jj = c0 - 6144;
    vws[b * NKV * HD + jj]     = sx + bv[jj];
    vws[b * NKV * HD + jj + 1] = sy + bv[jj + 1];
  }
}

// ---------------------------------------------------------------------------
// Phase B: flash-decode partials with K staged via global_load_lds DMA.
// Block = (b,h,chunk of 64 t), 4 waves. Each wave issues 8x 1-KB K DMAs
// (per-lane global src rotated by (row&3)*16B so LDS reads are 2-way bank-
// aliased = free), syncthreads drains vmcnt, then:
//   P1: scores from K_lds (16-lane groups, 4-stage shuffle) -> raw s in LDS
//   P2: block softmax (max, exp, sums) in LDS
//   P3: V streamed from global (dependency-free FMA), p broadcast from LDS
// smO aliases K_lds (K dead after P1). t=4095 K/V come from fresh kws/vws.
// ---------------------------------------------------------------------------
__global__ __launch_bounds__(256) void attn_partial_k(
    const float* __restrict__ ck, const float* __restrict__ cv,
    const float* __restrict__ qws, const float* __restrict__ kws,
    const float* __restrict__ vws, float* __restrict__ pM,
    float* __restrict__ pL, float* __restrict__ pO) {
  const int blk   = blockIdx.x;
  const int chunk = blk & (NCHB - 1);
  const int bh    = blk / NCHB;
  const int h     = bh & (NKV - 1);
  const int b     = bh / NKV;
  const int tid   = threadIdx.x;
  const int w     = tid >> 6;
  const int lane  = tid & 63;
  const int g     = lane >> 4;     // 16-lane group = one row per step
  const int sl    = lane & 15;     // owns d-range [8*sl, 8*sl+8)
  const int t0    = chunk * CH_T;

  __shared__ float K_lds[CH_T * HD];      // 32 KB; aliased as smO after P1
  __shared__ float s_lds[CH_T * NREP];    // raw scores, then p-values
  __shared__ float red[NREP * 8];
  __shared__ float Msh[NREP], Lsh[NREP];

  // ---- K DMA: 8 instrs/wave, rows 2i,2i+1 per instr, rotated source ----
  {
    const int hv  = lane >> 5;          // which of the 2 rows in this instr
    const int l32 = lane & 31;
#pragma unroll
    for (int ii = 0; ii < 8; ++ii) {
      const int i  = w * 8 + ii;        // 1-KB instr index
      const int r  = 2 * i + hv;        // local row 0..63
      const int tg = t0 + r;
      const float* rowb = (tg == NEWT)
          ? (kws + (b * NKV + h) * HD)
          : (ck + (((size_t)b * KLEN + tg) * NKV + h) * HD);
      const float* src = rowb + 4 * ((l32 - (r & 3)) & 31);
      gload_lds16(src, &K_lds[i * 256]);
    }
  }

  float4 qa[NREP], qb[NREP];
#pragma unroll
  for (int rr = 0; rr < NREP; ++rr) {
    const float* qp = &qws[b * DIM + (h * NREP + rr) * HD + 8 * sl];
    qa[rr] = *(const float4*)qp;
    qb[rr] = *(const float4*)(qp + 4);
  }

  __syncthreads();   // vmcnt(0)+barrier: K_lds fully populated

  // ---- P1: scores from LDS ----
#pragma unroll
  for (int j = 0; j < 4; ++j) {
    const int r  = w * 16 + j * 4 + g;
    const int x0 = (sl * 8 + 4 * g) & 127;        // rot(r)=16B*(r&3), r&3==g
    const float4 k0 = *(const float4*)&K_lds[r * HD + x0];
    const float4 k1 = *(const float4*)&K_lds[r * HD + ((x0 + 4) & 127)];
    float s[NREP];
#pragma unroll
    for (int rr = 0; rr < NREP; ++rr) {
      s[rr] = qa[rr].x * k0.x + qa[rr].y * k0.y + qa[rr].z * k0.z + qa[rr].w * k0.w
            + qb[rr].x * k1.x + qb[rr].y * k1.y + qb[rr].z * k1.z + qb[rr].w * k1.w;
    }
#pragma unroll
    for (int off = 1; off < 16; off <<= 1) {
#pragma unroll
      for (int rr = 0; rr < NREP; ++rr) s[rr] += __shfl_xor(s[rr], off, 64);
    }
    float sv = (sl == 0) ? s[0] : (sl == 1) ? s[1] : (sl == 2) ? s[2]
             : (sl == 3) ? s[3] : s[4];
    if (sl < NREP) s_lds[r * NREP + sl] = sv;
  }
  __syncthreads();

  // ---- P2: block softmax ----
  if (tid < NREP * 8) {                      // (a) segment maxima (8 rows/seg)
    const int rr = tid >> 3, seg = tid & 7;
    float mx = -1e30f;
#pragma unroll
    for (int k = 0; k < 8; ++k) mx = fmaxf(mx, s_lds[(seg * 8 + k) * NREP + rr]);
    red[tid] = mx;
  }
  __syncthreads();
  if (tid < NREP) {                          // (b) final max
    float mx = red[tid * 8];
#pragma unroll
    for (int k = 1; k < 8; ++k) mx = fmaxf(mx, red[tid * 8 + k]);
    Msh[tid] = mx;
  }
  __syncthreads();
  for (int idx = tid; idx < CH_T * NREP; idx += 256)   // (c) p = exp(s-M)
    s_lds[idx] = __expf(s_lds[idx] - Msh[idx % NREP]);
  __syncthreads();
  if (tid < NREP * 8) {                      // (d) segment sums
    const int rr = tid >> 3, seg = tid & 7;
    float sm = 0.f;
#pragma unroll
    for (int k = 0; k < 8; ++k) sm += s_lds[(seg * 8 + k) * NREP + rr];
    red[tid] = sm;
  }
  __syncthreads();
  if (tid < NREP) {                          // (e) row sum
    float L = 0.f;
#pragma unroll
    for (int k = 0; k < 8; ++k) L += red[tid * 8 + k];
    Lsh[tid] = L;
  }

  // ---- P3: PV streaming from global ----
  float o[NREP][8];
#pragma unroll
  for (int rr = 0; rr < NREP; ++rr)
#pragma unroll
    for (int j = 0; j < 8; ++j) o[rr][j] = 0.f;

  const bool tailw = (chunk == NCHB - 1) && (w == 3);  // rows 60..63 incl 4095
  const int  jmax  = tailw ? 3 : 4;
  {
    const float* vp = cv + (((size_t)b * KLEN + (t0 + w * 16 + g)) * NKV + h) * HD + 8 * sl;
#pragma unroll
    for (int j = 0; j < jmax; ++j) {
      const float4 va = *(const float4*)vp;
      const float4 vb = *(const float4*)(vp + 4);
      const int r = w * 16 + j * 4 + g;
      float p[NREP];
#pragma unroll
      for (int rr = 0; rr < NREP; ++rr) p[rr] = s_lds[r * NREP + rr];  // bcast
      const float vv[8] = {va.x, va.y, va.z, va.w, vb.x, vb.y, vb.z, vb.w};
#pragma unroll
      for (int rr = 0; rr < NREP; ++rr)
#pragma unroll
        for (int jj = 0; jj < 8; ++jj) o[rr][jj] = fmaf(p[rr], vv[jj], o[rr][jj]);
      vp += (size_t)4 * NKV * HD;
    }
    if (tailw) {
      const int r  = 60 + g;
      const int tg = t0 + r;                 // 4092..4095
      const float* vr = (tg == NEWT) ? (vws + (b * NKV + h) * HD)
                                     : (cv + (((size_t)b * KLEN + tg) * NKV + h) * HD);
      const float4 va = *(const float4*)(vr + 8 * sl);
      const float4 vb = *(const float4*)(vr + 8 * sl + 4);
      float p[NREP];
#pragma unroll
      for (int rr = 0; rr < NREP; ++rr) p[rr] = s_lds[r * NREP + rr];
      const float vv[8] = {va.x, va.y, va.z, va.w, vb.x, vb.y, vb.z, vb.w};
#pragma unroll
      for (int rr = 0; rr < NREP; ++rr)
#pragma unroll
        for (int jj = 0; jj < 8; ++jj) o[rr][jj] = fmaf(p[rr], vv[jj], o[rr][jj]);
    }
  }

  // merge 4 groups: plain sums (p normalized to the shared block max)
#pragma unroll
  for (int off = 16; off <= 32; off <<= 1) {
#pragma unroll
    for (int rr = 0; rr < NREP; ++rr)
#pragma unroll
      for (int jj = 0; jj < 8; ++jj) o[rr][jj] += __shfl_xor(o[rr][jj], off, 64);
  }

  float* smO = K_lds;                        // alias: [4][NREP][HD]
  if (g == 0) {
#pragma unroll
    for (int rr = 0; rr < NREP; ++rr) {
      float* sp = &smO[(w * NREP + rr) * HD + 8 * sl];
      *(float4*)sp       = make_float4(o[rr][0], o[rr][1], o[rr][2], o[rr][3]);
      *(float4*)(sp + 4) = make_float4(o[rr][4], o[rr][5], o[rr][6], o[rr][7]);
    }
  }
  __syncthreads();

  if (tid < HD) {
    const int d  = tid;
    const int pb = bh * NCHB + chunk;
#pragma unroll
    for (int rr = 0; rr < NREP; ++rr) {
      float acc = smO[rr * HD + d] + smO[(NREP + rr) * HD + d]
                + smO[(2 * NREP + rr) * HD + d] + smO[(3 * NREP + rr) * HD + d];
      pO[((size_t)pb * NREP + rr) * HD + d] = acc;
      if (d == 0) { pM[pb * NREP + rr] = Msh[rr]; pL[pb * NREP + rr] = Lsh[rr]; }
    }
  }
}

// ---------------------------------------------------------------------------
// Phase B2: combine NPART partials per (b,h) with exp rescale.
// ---------------------------------------------------------------------------
__global__ __launch_bounds__(256) void attn_combine_k(
    const float* __restrict__ pM, const float* __restrict__ pL,
    const float* __restrict__ pO, float* __restrict__ attn) {
  const int bh  = blockIdx.x;
  const int h   = bh & (NKV - 1);
  const int b   = bh / NKV;
  const int tid = threadIdx.x;
  __shared__ float ml[NREP * NPART], ll[NREP * NPART];
  __shared__ float wgt[NREP * NPART];
  __shared__ float Linv[NREP];

  for (int idx = tid; idx < NREP * NPART; idx += 256) {
    int r = idx / NPART, w = idx - r * NPART;
    ml[idx] = pM[(bh * NPART + w) * NREP + r];
    ll[idx] = pL[(bh * NPART + w) * NREP + r];
  }
  __syncthreads();
  for (int idx = tid; idx < NREP * NPART; idx += 256) {
    int r = idx / NPART;
    float M = -1e30f;
    for (int w = 0; w < NPART; ++w) M = fmaxf(M, ml[r * NPART + w]);
    float e = __expf(ml[idx] - M);
    wgt[idx] = e;
    ll[idx] *= e;
  }
  __syncthreads();
  if (tid < NREP) {
    float L = 0.f;
    for (int w = 0; w < NPART; ++w) L += ll[tid * NPART + w];
    Linv[tid] = 1.f / L;
  }
  __syncthreads();

  for (int oidx = tid; oidx < NREP * HD; oidx += 256) {
    int r = oidx >> 7, d = oidx & 127;
    float acc = 0.f;
    for (int w = 0; w < NPART; ++w)
      acc += wgt[r * NPART + w] * pO[((size_t)(bh * NPART + w) * NREP + r) * HD + d];
    attn[b * DIM + (h * NREP + r) * HD + d] = acc * Linv[r];
  }
}

// ---------------------------------------------------------------------------
// Phase C: output projection GEMV (split-K, 2 cols/thread) + reduce with bias.
// ---------------------------------------------------------------------------
__global__ __launch_bounds__(256) void out_partial_k(
    const float* __restrict__ attn, const float* __restrict__ wo,
    float* __restrict__ part) {
  const int cb = blockIdx.x % 10;
  const int kc = blockIdx.x / 10;
  const int c0 = cb * 512 + threadIdx.x * 2;

  const int i0 = kc * KCH;
  float ax[BS], ay[BS];
#pragma unroll
  for (int b = 0; b < BS; ++b) { ax[b] = 0.f; ay[b] = 0.f; }

  const float* wp = wo + (size_t)i0 * DIM + c0;
  const float* xp = attn + i0;
#pragma unroll 4
  for (int ii = 0; ii < KCH; ++ii) {
    const float2 wv2 = *(const float2*)&wp[(size_t)ii * DIM];
#pragma unroll
    for (int b = 0; b < BS; ++b) {
      const float xb = xp[b * DIM + ii];   // wave-uniform -> scalar load
      ax[b] = fmaf(xb, wv2.x, ax[b]);
      ay[b] = fmaf(xb, wv2.y, ay[b]);
    }
  }
#pragma unroll
  for (int b = 0; b < BS; ++b)
    *(float2*)&part[((size_t)kc * BS + b) * DIM + c0] = make_float2(ax[b], ay[b]);
}

__global__ __launch_bounds__(256) void out_reduce_k(
    const float* __restrict__ part, const float* __restrict__ bo,
    float* __restrict__ out) {
  int g = blockIdx.x * 256 + threadIdx.x;
  if (g >= BS * DIM) return;
  int b = g / DIM, c = g - b * DIM;
  float s = 0.f;
  for (int kc = 0; kc < NKC; ++kc) s += part[((size_t)kc * BS + b) * DIM + c];
  out[g] = s + bo[c];
}

// ---------------------------------------------------------------------------
extern "C" void kernel_launch(void* const* d_in, const int* in_sizes, int n_in,
                              void* d_out, int out_size, void* d_ws, size_t ws_size,
                              hipStream_t stream) {
  const float* x  = (const float*)d_in[0];
  // d_in[1] = start_pos (hardcoded 4095 per problem constants)
  const float* fc = (const float*)d_in[2];
  const float* ck = (const float*)d_in[3];
  const float* cv = (const float*)d_in[4];
  const float* wq = (const float*)d_in[5];
  const float* bq = (const float*)d_in[6];
  const float* wk = (const float*)d_in[7];
  const float* bk = (const float*)d_in[8];
  const float* wv = (const float*)d_in[9];
  const float* bv = (const float*)d_in[10];
  const float* wo = (const float*)d_in[11];
  const float* bo = (const float*)d_in[12];

  float* ws      = (float*)d_ws;
  float* qws     = ws + WS_Q;
  float* kws     = ws + WS_K;
  float* vws     = ws + WS_V;
  float* attn    = ws + WS_ATTN;
  float* scratch = ws + WS_SCRATCH;

  // Phase A: QKV projection
  qkv_partial_k<<<14 * NKC, 256, 0, stream>>>(x, wq, wk, wv, scratch);
  qkv_reduce_k<<<(BS * (ODQKV / 2) + 255) / 256, 256, 0, stream>>>(
      scratch, bq, bk, bv, fc, qws, kws, vws);

  // Phase B: attention (scratch reused for softmax partials)
  float* pM = scratch;                          // 64*NPART*NREP
  float* pL = pM + 64 * NPART * NREP;
  float* pO = pL + 64 * NPART * NREP;           // 64*NPART*NREP*HD floats
  attn_partial_k<<<64 * NCHB, 256, 0, stream>>>(ck, cv, qws, kws, vws, pM, pL, pO);
  attn_combine_k<<<64, 256, 0, stream>>>(pM, pL, pO, attn);

  // Phase C: output projection (scratch reused for GEMV partials)
  out_partial_k<<<10 * NKC, 256, 0, stream>>>(attn, wo, scratch);
  out_reduce_k<<<(BS * DIM + 255) / 256, 256, 0, stream>>>(scratch, bo, (float*)d_out);
}